// Round 14
// baseline (591.730 us; speedup 1.0000x reference)
//
#include <hip/hip_runtime.h>
#include <stdint.h>

// ---------------------------------------------------------------------------
// TransformerBlock on MI355X (gfx950)
//   x1  = x + ((softmax_causal((ln1(x)@qk)@ln1(x)^T / 32))@ln1(x))@ov
//   out = x1 + lrelu(lrelu(lrelu(ln2(x1)@W_up^T+b_up)@W_h^T+b_h)@W_down^T+b_down)
// GEMM engines:
//   gemm_nt8  (256x256, quad-buffer counted-vmcnt + m201-style sub-phases:
//              reads|stage|barrier|lgkmcnt(0)|16-MFMA|barrier): up, W_h, scores
//   gemm_nt8b (256x128, R12-proven single-phase schedule): q, ov, down, PV
//   gemm_nt   (128x128 2-phase m97): small-ws fallbacks only
// x1 lives in d_out.  T1 XCD swizzle everywhere; T2 LDS swizzle in nt8/nt8b.
// ---------------------------------------------------------------------------

typedef __attribute__((ext_vector_type(4))) float  f32x4;
typedef __attribute__((ext_vector_type(8))) __bf16 bf16v8;
typedef __attribute__((ext_vector_type(8))) unsigned short u16x8;
typedef unsigned short ushort_t;   // bf16 bit storage
typedef unsigned int   u32;

#define SLOPE 0.01f

__device__ __forceinline__ ushort_t f2bf(float f) {
  u32 u = __builtin_bit_cast(u32, f);
  u32 r = (u + 0x7FFFu + ((u >> 16) & 1u)) >> 16;
  return (ushort_t)r;
}
__device__ __forceinline__ float bf2f(ushort_t b) {
  u32 u = ((u32)b) << 16;
  return __builtin_bit_cast(float, u);
}

__device__ __forceinline__ void gload_lds16(const void* g, void* l) {
  __builtin_amdgcn_global_load_lds(
      (const __attribute__((address_space(1))) u32*)g,
      (__attribute__((address_space(3))) u32*)l, 16, 0, 0);
}

// ===========================================================================
// gemm_nt8: 256x256 8-wave quad-buffered NT GEMM, m201-style sub-phases.
// BK=32; LDS = 4 bufs x {A[256][32], B[256][32]} = 128 KB.
// Swizzle (T2, rule-21): global slot = slot ^ ((row>>1)&3), reads same XOR.
// Tile t = 2 sub-phases (template skeleton, faithful):
//  sub-A: {8 ds_read (av0-3, bv0-3) | 2 gload A-half(t+3) | barrier |
//          lgkmcnt(0)+sched_barrier | setprio 16 MFMA (mf0-3) | barrier}
//  sub-B: {4 ds_read (av4-7) | 2 gload B-half(t+3) | barrier |
//          lgkmcnt(0)+sched_barrier | setprio 16 MFMA (mf4-7) |
//          vmcnt(8/4/0 tail) | barrier}
// Mechanism: reads issue BEFORE the barrier, wait lands AFTER it -> ds_read
// latency hides under barrier-arrival spread + other waves' MFMA; MFMA
// clusters run with zero lgkm stalls; 2 barriers/16-MFMA give setprio a
// role-split to arbitrate (T5 gate).
// Liveness (strictly >= R6 safety: barriers only added): 4 gloads/tile in
// FIFO tile order; vmcnt(8) at tile end retires tile t+1's group before its
// reads; STAGE(t+3) overwrites buf[(t-1)&3] whose reads completed before
// phase t-1's final barrier.  CAUSAL: skip tiles n0 > m0+255.  Batched z.
// EPI: 0 = bf16 | 2 = bias+lrelu -> bf16.
// ===========================================================================
template<int EPI, bool CAUSAL>
__global__ __launch_bounds__(512, 1)
void gemm_nt8(const ushort_t* __restrict__ A, const ushort_t* __restrict__ B,
              void* __restrict__ Cv, const float* __restrict__ bias,
              int M, int N, int K, long sAb, long sBb, long sCb)
{
  extern __shared__ char smem[];
  const ushort_t* lds = (const ushort_t*)smem;
  const int tid = threadIdx.x;
  const int l   = tid & 63;
  const int nwg = gridDim.x * gridDim.y;
  const int orig = blockIdx.y * gridDim.x + blockIdx.x;
  const int q8 = nwg >> 3, r8 = nwg & 7;
  const int xcd = orig & 7, io = orig >> 3;
  const int logical = (xcd < r8 ? xcd * (q8 + 1) : r8 * (q8 + 1) + (xcd - r8) * q8) + io;
  const int m0 = (logical / gridDim.x) * 256;
  const int n0 = (logical % gridDim.x) * 256;
  if (CAUSAL && n0 > m0 + 255) return;
  A += (long)blockIdx.z * sAb;
  B += (long)blockIdx.z * sBb;
  const long coff = (long)blockIdx.z * sCb;
  const int wid = tid >> 6;
  const int wm = (wid >> 2) * 128;
  const int wn = (wid & 3) * 64;
  const int nt = K >> 5;

  const int  sg      = (((tid & 3) ^ ((tid >> 3) & 3))) * 8;
  const long rowA0   = (long)(m0 +       (tid >> 2)) * K;
  const long rowA1   = (long)(m0 + 128 + (tid >> 2)) * K;
  const long rowB0   = (long)(n0 +       (tid >> 2)) * K;
  const long rowB1   = (long)(n0 + 128 + (tid >> 2)) * K;
  const int  wbase16 = (tid & ~63) * 16;

#define STAGE_AH(TT) do {                                                     \
    const long _k  = (long)(TT) * 32;                                         \
    char* _ra = (char*)smem + ((TT) & 3) * 32768 + wbase16;                   \
    gload_lds16(A + rowA0 + _k + sg, _ra);                                    \
    gload_lds16(A + rowA1 + _k + sg, _ra + 8192);                             \
  } while (0)
#define STAGE_BH(TT) do {                                                     \
    const long _k  = (long)(TT) * 32;                                         \
    char* _rb = (char*)smem + ((TT) & 3) * 32768 + 16384 + wbase16;           \
    gload_lds16(B + rowB0 + _k + sg, _rb);                                    \
    gload_lds16(B + rowB1 + _k + sg, _rb + 8192);                             \
  } while (0)

  const int fr  = l & 15;
  const int fsl = (((l >> 4) ^ ((l >> 1) & 3))) * 8;

  f32x4 acc[8][4] = {};

  STAGE_AH(0); STAGE_BH(0);
  if (nt > 1) { STAGE_AH(1); STAGE_BH(1); }
  if (nt > 2) { STAGE_AH(2); STAGE_BH(2); }
  if (nt > 2)      { asm volatile("s_waitcnt vmcnt(8)" ::: "memory"); }
  else if (nt > 1) { asm volatile("s_waitcnt vmcnt(4)" ::: "memory"); }
  else             { asm volatile("s_waitcnt vmcnt(0)" ::: "memory"); }
  __builtin_amdgcn_s_barrier();
  __builtin_amdgcn_sched_barrier(0);

  for (int t = 0; t < nt; ++t) {
    const int buf = t & 3;
    const ushort_t* rA = lds + buf * 16384 +        (wm + fr) * 32 + fsl;
    const ushort_t* rB = lds + buf * 16384 + 8192 + (wn + fr) * 32 + fsl;
    bf16v8 av[8], bv[4];

    // ---- sub-phase A ----
#pragma unroll
    for (int mf = 0; mf < 4; mf++) av[mf] = *(const bf16v8*)(rA + mf * 512);
#pragma unroll
    for (int nf = 0; nf < 4; nf++) bv[nf] = *(const bf16v8*)(rB + nf * 512);
    if (t + 3 < nt) STAGE_AH(t + 3);
    __builtin_amdgcn_s_barrier();
    asm volatile("s_waitcnt lgkmcnt(0)" ::: "memory");
    __builtin_amdgcn_sched_barrier(0);
    __builtin_amdgcn_s_setprio(1);
#pragma unroll
    for (int mf = 0; mf < 4; mf++)
#pragma unroll
      for (int nf = 0; nf < 4; nf++)
        acc[mf][nf] = __builtin_amdgcn_mfma_f32_16x16x32_bf16(
            av[mf], bv[nf], acc[mf][nf], 0, 0, 0);
    __builtin_amdgcn_s_setprio(0);
    __builtin_amdgcn_s_barrier();

    // ---- sub-phase B ----
#pragma unroll
    for (int mf = 4; mf < 8; mf++) av[mf] = *(const bf16v8*)(rA + mf * 512);
    if (t + 3 < nt) STAGE_BH(t + 3);
    __builtin_amdgcn_s_barrier();
    asm volatile("s_waitcnt lgkmcnt(0)" ::: "memory");
    __builtin_amdgcn_sched_barrier(0);
    __builtin_amdgcn_s_setprio(1);
#pragma unroll
    for (int mf = 4; mf < 8; mf++)
#pragma unroll
      for (int nf = 0; nf < 4; nf++)
        acc[mf][nf] = __builtin_amdgcn_mfma_f32_16x16x32_bf16(
            av[mf], bv[nf], acc[mf][nf], 0, 0, 0);
    __builtin_amdgcn_s_setprio(0);

    // counted drain at tile end (identical accounting to R6/R8)
    if (t <= nt - 4) {
      asm volatile("s_waitcnt vmcnt(8)" ::: "memory");
      __builtin_amdgcn_s_barrier();
      __builtin_amdgcn_sched_barrier(0);
    } else if (t == nt - 3) {
      asm volatile("s_waitcnt vmcnt(4)" ::: "memory");
      __builtin_amdgcn_s_barrier();
      __builtin_amdgcn_sched_barrier(0);
    } else if (t == nt - 2) {
      asm volatile("s_waitcnt vmcnt(0)" ::: "memory");
      __builtin_amdgcn_s_barrier();
      __builtin_amdgcn_sched_barrier(0);
    }
  }
#undef STAGE_AH
#undef STAGE_BH

  const int lr = (l >> 4) * 4;
#pragma unroll
  for (int mf = 0; mf < 8; mf++) {
    const int row0 = m0 + wm + mf * 16 + lr;
#pragma unroll
    for (int nf = 0; nf < 4; nf++) {
      const int col = n0 + wn + nf * 16 + fr;
      const float bcol = (EPI == 2) ? bias[col] : 0.f;
#pragma unroll
      for (int r = 0; r < 4; r++) {
        float v = acc[mf][nf][r];
        if constexpr (EPI == 2) {
          v += bcol;
          v = v >= 0.f ? v : SLOPE * v;
          ((ushort_t*)Cv)[coff + (long)(row0 + r) * N + col] = f2bf(v);
        } else {
          ((ushort_t*)Cv)[coff + (long)(row0 + r) * N + col] = f2bf(v);
        }
      }
    }
  }
}

// ===========================================================================
// gemm_nt8b: 256x128 8-wave quad-buffered NT GEMM (R12-proven schedule,
// 3-load groups -> vmcnt 6/3/0).  Waves 4Mx2N of 64x64; acc[4][4].
// LDS = 4 bufs x {A[256][32] 16KB, B[128][32] 8KB} = 96 KB.
// KLIM: Keff = min(K, m0+256).  Batched via blockIdx.z strides.
// EPI: 0 = bf16 | 3 = +resid -> f32 | 4 = bias+lrelu+resid -> f32
// ===========================================================================
template<int EPI, bool KLIM>
__global__ __launch_bounds__(512, 1)
void gemm_nt8b(const ushort_t* __restrict__ A, const ushort_t* __restrict__ B,
               void* __restrict__ Cv, const float* __restrict__ bias,
               const float* __restrict__ resid,
               int M, int N, int K, long sAb, long sBb, long sCb)
{
  extern __shared__ char smem[];
  const ushort_t* lds = (const ushort_t*)smem;
  const int tid = threadIdx.x;
  const int l   = tid & 63;
  const int nwg = gridDim.x * gridDim.y;
  const int orig = blockIdx.y * gridDim.x + blockIdx.x;
  const int q8 = nwg >> 3, r8 = nwg & 7;
  const int xcd = orig & 7, io = orig >> 3;
  const int logical = (xcd < r8 ? xcd * (q8 + 1) : r8 * (q8 + 1) + (xcd - r8) * q8) + io;
  const int m0 = (logical / gridDim.x) * 256;
  const int n0 = (logical % gridDim.x) * 128;
  A += (long)blockIdx.z * sAb;
  B += (long)blockIdx.z * sBb;
  const long coff = (long)blockIdx.z * sCb;
  const int wid = tid >> 6;
  const int wm = (wid >> 1) * 64;
  const int wn = (wid & 1) * 64;
  int Keff = K;
  if (KLIM) Keff = min(K, m0 + 256);
  const int nt = Keff >> 5;

  const int  sg      = (((tid & 3) ^ ((tid >> 3) & 3))) * 8;
  const long rowA0   = (long)(m0 +       (tid >> 2)) * K;
  const long rowA1   = (long)(m0 + 128 + (tid >> 2)) * K;
  const long rowB0   = (long)(n0 +       (tid >> 2)) * K;
  const int  wbase16 = (tid & ~63) * 16;

#define STAGEB(TT) do {                                                       \
    const long _k  = (long)(TT) * 32;                                         \
    char* _ra = (char*)smem + ((TT) & 3) * 24576 + wbase16;                   \
    char* _rb = _ra + 16384;                                                  \
    gload_lds16(A + rowA0 + _k + sg, _ra);                                    \
    gload_lds16(A + rowA1 + _k + sg, _ra + 8192);                             \
    gload_lds16(B + rowB0 + _k + sg, _rb);                                    \
  } while (0)

  const int fr  = l & 15;
  const int fsl = (((l >> 4) ^ ((l >> 1) & 3))) * 8;

  f32x4 acc[4][4] = {};

  STAGEB(0);
  if (nt > 1) STAGEB(1);
  if (nt > 2) STAGEB(2);
  if (nt > 2)      { asm volatile("s_waitcnt vmcnt(6)" ::: "memory"); }
  else if (nt > 1) { asm volatile("s_waitcnt vmcnt(3)" ::: "memory"); }
  else             { asm volatile("s_waitcnt vmcnt(0)" ::: "memory"); }
  __builtin_amdgcn_s_barrier();
  __builtin_amdgcn_sched_barrier(0);

  for (int t = 0; t < nt; ++t) {
    const int buf = t & 3;
    const ushort_t* rA = lds + buf * 12288 +        (wm + fr) * 32 + fsl;
    const ushort_t* rB = lds + buf * 12288 + 8192 + (wn + fr) * 32 + fsl;
    bf16v8 av[4], bv[4];
#pragma unroll
    for (int mf = 0; mf < 4; mf++) av[mf] = *(const bf16v8*)(rA + mf * 512);
#pragma unroll
    for (int nf = 0; nf < 4; nf++) bv[nf] = *(const bf16v8*)(rB + nf * 512);

    if (t + 3 < nt) STAGEB(t + 3);

    __builtin_amdgcn_s_setprio(1);
#pragma unroll
    for (int mf = 0; mf < 4; mf++)
#pragma unroll
      for (int nf = 0; nf < 4; nf++)
        acc[mf][nf] = __builtin_amdgcn_mfma_f32_16x16x32_bf16(
            av[mf], bv[nf], acc[mf][nf], 0, 0, 0);
    __builtin_amdgcn_s_setprio(0);

    if (t <= nt - 4) {
      asm volatile("s_waitcnt vmcnt(6)" ::: "memory");
      __builtin_amdgcn_s_barrier();
      __builtin_amdgcn_sched_barrier(0);
    } else if (t == nt - 3) {
      asm volatile("s_waitcnt vmcnt(3)" ::: "memory");
      __builtin_amdgcn_s_barrier();
      __builtin_amdgcn_sched_barrier(0);
    } else if (t == nt - 2) {
      asm volatile("s_waitcnt vmcnt(0)" ::: "memory");
      __builtin_amdgcn_s_barrier();
      __builtin_amdgcn_sched_barrier(0);
    }
  }
#undef STAGEB

  const int lr = (l >> 4) * 4;
#pragma unroll
  for (int mf = 0; mf < 4; mf++) {
    const int row0 = m0 + wm + mf * 16 + lr;
#pragma unroll
    for (int nf = 0; nf < 4; nf++) {
      const int col = n0 + wn + nf * 16 + fr;
      const float bcol = (EPI == 4) ? bias[col] : 0.f;
#pragma unroll
      for (int r = 0; r < 4; r++) {
        float v = acc[mf][nf][r];
        const long idx = coff + (long)(row0 + r) * N + col;
        if constexpr (EPI == 0) {
          ((ushort_t*)Cv)[idx] = f2bf(v);
        } else if constexpr (EPI == 3) {
          ((float*)Cv)[idx] = v + resid[idx];
        } else {  // EPI == 4
          v += bcol;
          v = v >= 0.f ? v : SLOPE * v;
          ((float*)Cv)[idx] = v + resid[idx];
        }
      }
    }
  }
}

// ---------------------------------------------------------------------------
// m97-style 128x128 NT GEMM (4 waves, BK=32), XCD-swizzled grid.
// Fallback tiers only.
// ---------------------------------------------------------------------------
template<int EPI, bool CAUSAL, bool KLIM>
__global__ __launch_bounds__(256)
void gemm_nt(const ushort_t* __restrict__ A, const ushort_t* __restrict__ B,
             void* __restrict__ Cv, const float* __restrict__ bias,
             const float* __restrict__ resid,
             int M, int N, int K, long sAb, long sBb, long sCb)
{
  __shared__ ushort_t lA[128 * 32];
  __shared__ ushort_t lB[128 * 32];
  const int tid = threadIdx.x;
  const int w = tid >> 6;
  const int l = tid & 63;
  const int nwg = gridDim.x * gridDim.y;
  const int orig = blockIdx.y * gridDim.x + blockIdx.x;
  const int q8 = nwg >> 3, r8 = nwg & 7;
  const int xcd = orig & 7, io = orig >> 3;
  const int logical = (xcd < r8 ? xcd * (q8 + 1) : r8 * (q8 + 1) + (xcd - r8) * q8) + io;
  const int m0 = (logical / gridDim.x) * 128;
  const int n0 = (logical % gridDim.x) * 128;
  if (CAUSAL && n0 > m0 + 127) return;
  const long bz = blockIdx.z;
  A += bz * sAb;
  B += bz * sBb;
  int Keff = K;
  if (KLIM) Keff = min(K, m0 + 128);

  const ushort_t* gA = A + (long)(m0 + w * 32 + (l >> 2)) * K + (l & 3) * 8;
  const ushort_t* gB = B + (long)(n0 + w * 32 + (l >> 2)) * K + (l & 3) * 8;
  ushort_t* lAw0 = &lA[(w * 32) * 32];
  ushort_t* lAw1 = &lA[(w * 32 + 16) * 32];
  ushort_t* lBw0 = &lB[(w * 32) * 32];
  ushort_t* lBw1 = &lB[(w * 32 + 16) * 32];
  const int wm = (w >> 1) * 64, wn = (w & 1) * 64;

  f32x4 acc[4][4] = {};

  for (int k0 = 0; k0 < Keff; k0 += 32) {
    gload_lds16(gA,                 lAw0);
    gload_lds16(gA + (long)16 * K,  lAw1);
    gload_lds16(gB,                 lBw0);
    gload_lds16(gB + (long)16 * K,  lBw1);
    gA += 32; gB += 32;
    __syncthreads();

    bf16v8 af[4], bfr[4];
#pragma unroll
    for (int m = 0; m < 4; m++)
      af[m] = *(const bf16v8*)&lA[(wm + m * 16 + (l & 15)) * 32 + (l >> 4) * 8];
#pragma unroll
    for (int n = 0; n < 4; n++)
      bfr[n] = *(const bf16v8*)&lB[(wn + n * 16 + (l & 15)) * 32 + (l >> 4) * 8];
#pragma unroll
    for (int m = 0; m < 4; m++)
#pragma unroll
      for (int n = 0; n < 4; n++)
        acc[m][n] = __builtin_amdgcn_mfma_f32_16x16x32_bf16(af[m], bfr[n], acc[m][n], 0, 0, 0);
    __syncthreads();
  }

  const int lr = (l >> 4) * 4;
  const int lc = l & 15;
#pragma unroll
  for (int m = 0; m < 4; m++) {
    const int row0 = m0 + wm + m * 16 + lr;
#pragma unroll
    for (int n = 0; n < 4; n++) {
      const int col = n0 + wn + n * 16 + lc;
#pragma unroll
      for (int r = 0; r < 4; r++) {
        float v = acc[m][n][r];
        const long idx = bz * sCb + (long)(row0 + r) * N + col;
        if constexpr (EPI == 0) {
          ((ushort_t*)Cv)[idx] = f2bf(v);
        } else if constexpr (EPI == 2) {
          v += bias[col];
          v = v >= 0.f ? v : SLOPE * v;
          ((ushort_t*)Cv)[idx] = f2bf(v);
        } else if constexpr (EPI == 3) {
          ((float*)Cv)[idx] = v + resid[idx];
        } else {
          v += bias[col];
          v = v >= 0.f ? v : SLOPE * v;
          ((float*)Cv)[idx] = v + resid[idx];
        }
      }
    }
  }
}

// ---------------------------------------------------------------------------
// LayerNorm: one 256-thread block per 1024-f32 row -> bf16 out
// ---------------------------------------------------------------------------
__global__ __launch_bounds__(256)
void ln_kernel(const float* __restrict__ x, const float* __restrict__ g,
               const float* __restrict__ bta, ushort_t* __restrict__ o)
{
  const long row = blockIdx.x;
  const int tid = threadIdx.x;
  const float4 v = *((const float4*)(x + row * 1024) + tid);
  float s  = v.x + v.y + v.z + v.w;
  float ss = v.x * v.x + v.y * v.y + v.z * v.z + v.w * v.w;
  for (int o2 = 32; o2 > 0; o2 >>= 1) {
    s  += __shfl_down(s, o2);
    ss += __shfl_down(ss, o2);
  }
  __shared__ float rs[4], rss[4];
  const int w = tid >> 6, l = tid & 63;
  if (l == 0) { rs[w] = s; rss[w] = ss; }
  __syncthreads();
  if (tid == 0) {
    float a = 0, c = 0;
    for (int i = 0; i < 4; i++) { a += rs[i]; c += rss[i]; }
    rs[0] = a; rss[0] = c;
  }
  __syncthreads();
  const float mean = rs[0] * (1.f / 1024.f);
  const float var  = rss[0] * (1.f / 1024.f) - mean * mean;
  const float rstd = rsqrtf(var + 1e-5f);
  const int c0 = tid * 4;
  ushort_t* orow = o + row * 1024;
  const float* vp = (const float*)&v;
#pragma unroll
  for (int i = 0; i < 4; i++)
    orow[c0 + i] = f2bf((vp[i] - mean) * rstd * g[c0 + i] + bta[c0 + i]);
}

// ---------------------------------------------------------------------------
// Causal softmax, IN PLACE on bf16 scores (scale 1/32), zero-fill t>s.
// ---------------------------------------------------------------------------
__global__ __launch_bounds__(256)
void softmax_kernel(ushort_t* __restrict__ sc)
{
  const long row = blockIdx.x;
  const int s = (int)(row & 2047);
  const int tid = threadIdx.x;
  ushort_t* srow = sc + row * 2048;
  const int t0 = tid * 8;
  u16x8 raw = *(const u16x8*)(srow + t0);
  float v[8];
  const float rsc = 1.0f / 32.0f;
  float mx = -3e38f;
#pragma unroll
  for (int i = 0; i < 8; i++) {
    float f = bf2f(raw[i]) * rsc;
    v[i] = (t0 + i <= s) ? f : -3e38f;
    mx = fmaxf(mx, v[i]);
  }
  for (int o = 32; o > 0; o >>= 1) mx = fmaxf(mx, __shfl_down(mx, o));
  __shared__ float red[8];
  const int w = tid >> 6, l = tid & 63;
  if (l == 0) red[w] = mx;
  __syncthreads();
  if (tid == 0) {
    float m2 = red[0];
    for (int i = 1; i < 4; i++) m2 = fmaxf(m2, red[i]);
    red[0] = m2;
  }
  __syncthreads();
  const float m = red[0];
  float sum = 0.f;
#pragma unroll
  for (int i = 0; i < 8; i++) {
    float e = (t0 + i <= s) ? __expf(v[i] - m) : 0.f;
    v[i] = e; sum += e;
  }
  for (int o = 32; o > 0; o >>= 1) sum += __shfl_down(sum, o);
  if (l == 0) red[4 + w] = sum;
  __syncthreads();
  if (tid == 0) {
    float s2 = 0;
    for (int i = 0; i < 4; i++) s2 += red[4 + i];
    red[0] = 1.0f / s2;
  }
  __syncthreads();
  const float inv = red[0];
#pragma unroll
  for (int i = 0; i < 8; i++) srow[t0 + i] = f2bf(v[i] * inv);
}

// ---------------------------------------------------------------------------
// Fused cast of all three MLP weights (one launch).
// ---------------------------------------------------------------------------
__global__ __launch_bounds__(256)
void cast3_bf16(const float* __restrict__ a, const float* __restrict__ b,
                const float* __restrict__ c, ushort_t* __restrict__ oa,
                ushort_t* __restrict__ ob, ushort_t* __restrict__ oc)
{
  long i = ((long)blockIdx.x * 256 + threadIdx.x) * 4;
  const float* src; ushort_t* dst;
  if (i < 4194304L)        { src = a; dst = oa; }
  else if (i < 8388608L)   { src = b + (0 - 4194304L); dst = ob - 4194304L; }
  else                     { src = c + (0 - 8388608L); dst = oc - 8388608L; }
  float4 v = *(const float4*)(src + i);
  dst[i]     = f2bf(v.x);
  dst[i + 1] = f2bf(v.y);
  dst[i + 2] = f2bf(v.z);
  dst[i + 3] = f2bf(v.w);
}

// Transpose-cast f32[1024][1024] -> bf16[1024][1024]^T for qk (z=0), ov (z=1)
__global__ __launch_bounds__(256)
void transpose_cast2(const float* __restrict__ s0, ushort_t* __restrict__ d0,
                     const float* __restrict__ s1, ushort_t* __restrict__ d1)
{
  __shared__ ushort_t t[32][33];
  const float* in = blockIdx.z ? s1 : s0;
  ushort_t*    o  = blockIdx.z ? d1 : d0;
  const int tx = threadIdx.x & 31, ty = threadIdx.x >> 5;
  const int r0 = blockIdx.y * 32, c0 = blockIdx.x * 32;
#pragma unroll
  for (int i = 0; i < 4; i++)
    t[ty + i * 8][tx] = f2bf(in[(long)(r0 + ty + i * 8) * 1024 + c0 + tx]);
  __syncthreads();
#pragma unroll
  for (int i = 0; i < 4; i++)
    o[(long)(c0 + ty + i * 8) * 1024 + r0 + tx] = t[tx][ty + i * 8];
}

// Transpose bf16[R][C] -> bf16[C][R], batched over z (h -> hT)
__global__ __launch_bounds__(256)
void transpose_bf16(const ushort_t* __restrict__ in, ushort_t* __restrict__ o,
                    int R, int C)
{
  __shared__ ushort_t t[32][33];
  const long bz = blockIdx.z;
  in += bz * (long)R * C;
  o  += bz * (long)R * C;
  const int tx = threadIdx.x & 31, ty = threadIdx.x >> 5;
  const int r0 = blockIdx.y * 32, c0 = blockIdx.x * 32;
#pragma unroll
  for (int i = 0; i < 4; i++)
    t[ty + i * 8][tx] = in[(long)(r0 + ty + i * 8) * C + c0 + tx];
  __syncthreads();
#pragma unroll
  for (int i = 0; i < 4; i++)
    o[(long)(c0 + ty + i * 8) * R + r0 + tx] = t[tx][ty + i * 8];
}

// ---------------------------------------------------------------------------
extern "C" void kernel_launch(void* const* d_in, const int* in_sizes, int n_in,
                              void* d_out, int out_size, void* d_ws, size_t ws_size,
                              hipStream_t stream)
{
  const float* x      = (const float*)d_in[0];
  const float* qk     = (const float*)d_in[1];
  const float* ov     = (const float*)d_in[2];
  const float* ln1_g  = (const float*)d_in[3];
  const float* ln1_b  = (const float*)d_in[4];
  const float* ln2_g  = (const float*)d_in[5];
  const float* ln2_b  = (const float*)d_in[6];
  const float* W_up   = (const float*)d_in[7];
  const float* b_up   = (const float*)d_in[8];
  const float* W_h    = (const float*)d_in[9];
  const float* b_h    = (const float*)d_in[10];
  const float* W_down = (const float*)d_in[11];
  const float* b_down = (const float*)d_in[12];
  float* out = (float*)d_out;          // also holds x1 (residual stream)
  char* ws = (char*)d_ws;
  const long MB = 1024L * 1024L;

  // Arena:
  ushort_t* wqT    = (ushort_t*)(ws +   0 * MB);
  ushort_t* woT    = (ushort_t*)(ws +   2 * MB);
  ushort_t* h      = (ushort_t*)(ws +   4 * MB);
  ushort_t* hT     = (ushort_t*)(ws +  20 * MB);
  ushort_t* q      = (ushort_t*)(ws +  36 * MB);
  ushort_t* scores = (ushort_t*)(ws +  52 * MB);
  ushort_t* h2     = h;
  ushort_t* attnh  = q;
  ushort_t* wu     = hT;
  ushort_t* wd     = (ushort_t*)(ws +  28 * MB);
  ushort_t* wh     = q;
  ushort_t* a1     = (ushort_t*)(ws +  68 * MB);
  ushort_t* a2c    = (ushort_t*)(ws + 100 * MB);
  ushort_t* a2f    = (ushort_t*)(ws + 132 * MB);

  const bool ws197 = ws_size >= (size_t)(197 * MB);
  const bool ws166 = ws_size >= (size_t)(166 * MB);

  // ---- Phase A: attention ----
  transpose_cast2<<<dim3(32, 32, 2), 256, 0, stream>>>(qk, wqT, ov, woT);
  ln_kernel<<<8192, 256, 0, stream>>>(x, ln1_g, ln1_b, h);
  transpose_bf16<<<dim3(32, 64, 4), 256, 0, stream>>>(h, hT, 2048, 1024);

  // q = h @ qk   (256x128 engine, grid 256)
  gemm_nt8b<0, false><<<dim3(8, 32, 1), 512, 98304, stream>>>(
      h, wqT, q, nullptr, nullptr, 8192, 1024, 1024, 0, 0, 0);
  // scores = q @ h^T  (256x256 engine, causal skip, batched)
  gemm_nt8<0, true><<<dim3(8, 8, 4), 512, 131072, stream>>>(
      q, h, scores, nullptr, 2048, 2048, 1024,
      2048L * 1024, 2048L * 1024, 2048L * 2048);
  // probs = causal softmax(scores/32), in place
  softmax_kernel<<<8192, 256, 0, stream>>>(scores);
  // attnh = probs @ h  (256x128 engine, KLIM, batched; B = hT)
  gemm_nt8b<0, true><<<dim3(8, 8, 4), 512, 98304, stream>>>(
      scores, hT, attnh, nullptr, nullptr, 2048, 1024, 2048,
      2048L * 2048, 1024L * 2048, 2048L * 1024);
  // x1 = x + attnh @ ov  -> stored in d_out  (256x128 engine)
  gemm_nt8b<3, false><<<dim3(8, 32, 1), 512, 98304, stream>>>(
      attnh, woT, out, nullptr, x, 8192, 1024, 1024, 0, 0, 0);

  // ---- Phase B: MLP ----
  ln_kernel<<<8192, 256, 0, stream>>>(out, ln2_g, ln2_b, h2);
  cast3_bf16<<<24576, 256, 0, stream>>>(W_up, W_down, W_h, wu, wd, wh);

  if (ws197) {
    gemm_nt8<2, false><<<dim3(16, 32, 1), 512, 131072, stream>>>(
        h2, wu, a1, b_up, 8192, 4096, 1024, 0, 0, 0);
    gemm_nt8<2, false><<<dim3(16, 32, 1), 512, 131072, stream>>>(
        a1, wh, a2f, b_h, 8192, 4096, 4096, 0, 0, 0);
    gemm_nt8b<4, false><<<dim3(8, 32, 1), 512, 98304, stream>>>(
        a2f, wd, out, b_down, out, 8192, 1024, 4096, 0, 0, 0);
  } else if (ws166) {
    for (int c = 0; c < 2; c++) {
      const long r0 = (long)c * 4096;
      gemm_nt8<2, false><<<dim3(16, 16, 1), 512, 131072, stream>>>(
          h2 + r0 * 1024, wu, a1, b_up, 4096, 4096, 1024, 0, 0, 0);
      gemm_nt8<2, false><<<dim3(16, 16, 1), 512, 131072, stream>>>(
          a1, wh, a2c + r0 * 4096, b_h, 4096, 4096, 4096, 0, 0, 0);
    }
    gemm_nt<4, false, false><<<dim3(8, 64, 1), 256, 0, stream>>>(
        a2c, wd, out, b_down, out, 8192, 1024, 4096, 0, 0, 0);
  } else {
    for (int c = 0; c < 2; c++) {
      const long r0 = (long)c * 4096;
      gemm_nt8<2, false><<<dim3(16, 16, 1), 512, 131072, stream>>>(
          h2 + r0 * 1024, wu, a1, b_up, 4096, 4096, 1024, 0, 0, 0);
      gemm_nt8<2, false><<<dim3(16, 16, 1), 512, 131072, stream>>>(
          a1, wh, a2c, b_h, 4096, 4096, 4096, 0, 0, 0);
      gemm_nt<4, false, false><<<dim3(8, 32, 1), 256, 0, stream>>>(
          a2c, wd, out + r0 * 1024, b_down, out + r0 * 1024, 4096, 1024, 4096, 0, 0, 0);
    }
  }
}

// Round 15
// 576.852 us; speedup vs baseline: 1.0258x; 1.0258x over previous
//
#include <hip/hip_runtime.h>
#include <stdint.h>

// ---------------------------------------------------------------------------
// TransformerBlock on MI355X (gfx950)  — R13 configuration (measured 580 us),
// reverted after R14's sub-phase split regressed (4th schedule-restructure
// failure: 241->269 us on W_h; single-phase counted-vmcnt is the optimum of
// this structure at 1 blk/CU).
//   x1  = x + ((softmax_causal((ln1(x)@qk)@ln1(x)^T / 32))@ln1(x))@ov
//   out = x1 + lrelu(lrelu(lrelu(ln2(x1)@W_up^T+b_up)@W_h^T+b_h)@W_down^T+b_down)
// GEMM engines (all quad-buffer counted-vmcnt, T1+T2, R8-proven schedule):
//   gemm_nt8  (256x256, 4-load groups, vmcnt 8/4/0): up, W_h, scores(causal,z)
//   gemm_nt8b (256x128, 3-load groups, vmcnt 6/3/0): q, ov, down, PV(KLIM,z)
//   gemm_nt   (128x128 2-phase m97): small-ws fallbacks only
// x1 lives in d_out.
// ---------------------------------------------------------------------------

typedef __attribute__((ext_vector_type(4))) float  f32x4;
typedef __attribute__((ext_vector_type(8))) __bf16 bf16v8;
typedef __attribute__((ext_vector_type(8))) unsigned short u16x8;
typedef unsigned short ushort_t;   // bf16 bit storage
typedef unsigned int   u32;

#define SLOPE 0.01f

__device__ __forceinline__ ushort_t f2bf(float f) {
  u32 u = __builtin_bit_cast(u32, f);
  u32 r = (u + 0x7FFFu + ((u >> 16) & 1u)) >> 16;
  return (ushort_t)r;
}
__device__ __forceinline__ float bf2f(ushort_t b) {
  u32 u = ((u32)b) << 16;
  return __builtin_bit_cast(float, u);
}

__device__ __forceinline__ void gload_lds16(const void* g, void* l) {
  __builtin_amdgcn_global_load_lds(
      (const __attribute__((address_space(1))) u32*)g,
      (__attribute__((address_space(3))) u32*)l, 16, 0, 0);
}

// ===========================================================================
// gemm_nt8: 256x256 8-wave quad-buffered NT GEMM (R8-proven schedule).
// BK=32; LDS = 4 bufs x {A[256][32], B[256][32]} = 128 KB.  4-load groups,
// vmcnt(8)/4/0.  T2 swizzle: global slot = slot ^ ((row>>1)&3), reads same.
// CAUSAL: skip tiles fully above diagonal (n0 > m0+255).  Batched via
// blockIdx.z strides.  EPI: 0 = bf16 | 2 = bias+lrelu -> bf16.
// ===========================================================================
template<int EPI, bool CAUSAL>
__global__ __launch_bounds__(512, 1)
void gemm_nt8(const ushort_t* __restrict__ A, const ushort_t* __restrict__ B,
              void* __restrict__ Cv, const float* __restrict__ bias,
              int M, int N, int K, long sAb, long sBb, long sCb)
{
  extern __shared__ char smem[];
  const ushort_t* lds = (const ushort_t*)smem;
  const int tid = threadIdx.x;
  const int l   = tid & 63;
  const int nwg = gridDim.x * gridDim.y;
  const int orig = blockIdx.y * gridDim.x + blockIdx.x;
  const int q8 = nwg >> 3, r8 = nwg & 7;
  const int xcd = orig & 7, io = orig >> 3;
  const int logical = (xcd < r8 ? xcd * (q8 + 1) : r8 * (q8 + 1) + (xcd - r8) * q8) + io;
  const int m0 = (logical / gridDim.x) * 256;
  const int n0 = (logical % gridDim.x) * 256;
  if (CAUSAL && n0 > m0 + 255) return;
  A += (long)blockIdx.z * sAb;
  B += (long)blockIdx.z * sBb;
  const long coff = (long)blockIdx.z * sCb;
  const int wid = tid >> 6;
  const int wm = (wid >> 2) * 128;
  const int wn = (wid & 3) * 64;
  const int nt = K >> 5;

  const int  sg      = (((tid & 3) ^ ((tid >> 3) & 3))) * 8;
  const long rowA0   = (long)(m0 +       (tid >> 2)) * K;
  const long rowA1   = (long)(m0 + 128 + (tid >> 2)) * K;
  const long rowB0   = (long)(n0 +       (tid >> 2)) * K;
  const long rowB1   = (long)(n0 + 128 + (tid >> 2)) * K;
  const int  wbase16 = (tid & ~63) * 16;

#define STAGE(TT) do {                                                        \
    const long _k  = (long)(TT) * 32;                                         \
    char* _ra = (char*)smem + ((TT) & 3) * 32768 + wbase16;                   \
    char* _rb = _ra + 16384;                                                  \
    gload_lds16(A + rowA0 + _k + sg, _ra);                                    \
    gload_lds16(A + rowA1 + _k + sg, _ra + 8192);                             \
    gload_lds16(B + rowB0 + _k + sg, _rb);                                    \
    gload_lds16(B + rowB1 + _k + sg, _rb + 8192);                             \
  } while (0)

  const int fr  = l & 15;
  const int fsl = (((l >> 4) ^ ((l >> 1) & 3))) * 8;

  f32x4 acc[8][4] = {};

  STAGE(0);
  if (nt > 1) STAGE(1);
  if (nt > 2) STAGE(2);
  if (nt > 2)      { asm volatile("s_waitcnt vmcnt(8)" ::: "memory"); }
  else if (nt > 1) { asm volatile("s_waitcnt vmcnt(4)" ::: "memory"); }
  else             { asm volatile("s_waitcnt vmcnt(0)" ::: "memory"); }
  __builtin_amdgcn_s_barrier();
  __builtin_amdgcn_sched_barrier(0);

  for (int t = 0; t < nt; ++t) {
    const int buf = t & 3;
    const ushort_t* rA = lds + buf * 16384 +        (wm + fr) * 32 + fsl;
    const ushort_t* rB = lds + buf * 16384 + 8192 + (wn + fr) * 32 + fsl;
    bf16v8 av[8], bv[4];
#pragma unroll
    for (int mf = 0; mf < 8; mf++) av[mf] = *(const bf16v8*)(rA + mf * 512);
#pragma unroll
    for (int nf = 0; nf < 4; nf++) bv[nf] = *(const bf16v8*)(rB + nf * 512);

    if (t + 3 < nt) STAGE(t + 3);

    __builtin_amdgcn_s_setprio(1);
#pragma unroll
    for (int mf = 0; mf < 8; mf++)
#pragma unroll
      for (int nf = 0; nf < 4; nf++)
        acc[mf][nf] = __builtin_amdgcn_mfma_f32_16x16x32_bf16(
            av[mf], bv[nf], acc[mf][nf], 0, 0, 0);
    __builtin_amdgcn_s_setprio(0);

    if (t <= nt - 4) {
      asm volatile("s_waitcnt vmcnt(8)" ::: "memory");
      __builtin_amdgcn_s_barrier();
      __builtin_amdgcn_sched_barrier(0);
    } else if (t == nt - 3) {
      asm volatile("s_waitcnt vmcnt(4)" ::: "memory");
      __builtin_amdgcn_s_barrier();
      __builtin_amdgcn_sched_barrier(0);
    } else if (t == nt - 2) {
      asm volatile("s_waitcnt vmcnt(0)" ::: "memory");
      __builtin_amdgcn_s_barrier();
      __builtin_amdgcn_sched_barrier(0);
    }
  }
#undef STAGE

  const int lr = (l >> 4) * 4;
#pragma unroll
  for (int mf = 0; mf < 8; mf++) {
    const int row0 = m0 + wm + mf * 16 + lr;
#pragma unroll
    for (int nf = 0; nf < 4; nf++) {
      const int col = n0 + wn + nf * 16 + fr;
      const float bcol = (EPI == 2) ? bias[col] : 0.f;
#pragma unroll
      for (int r = 0; r < 4; r++) {
        float v = acc[mf][nf][r];
        if constexpr (EPI == 2) {
          v += bcol;
          v = v >= 0.f ? v : SLOPE * v;
          ((ushort_t*)Cv)[coff + (long)(row0 + r) * N + col] = f2bf(v);
        } else {
          ((ushort_t*)Cv)[coff + (long)(row0 + r) * N + col] = f2bf(v);
        }
      }
    }
  }
}

// ===========================================================================
// gemm_nt8b: 256x128 8-wave quad-buffered NT GEMM (same schedule, 3-load
// groups -> vmcnt 6/3/0).  Waves 4Mx2N of 64x64; acc[4][4] = 64 VGPR.
// LDS = 4 bufs x {A[256][32] 16KB, B[128][32] 8KB} = 96 KB.
// KLIM: Keff = min(K, m0+256) (PV; probs zero-filled above diagonal).
// Batched via blockIdx.z strides.
// EPI: 0 = bf16 | 3 = +resid -> f32 | 4 = bias+lrelu+resid -> f32
// ===========================================================================
template<int EPI, bool KLIM>
__global__ __launch_bounds__(512, 1)
void gemm_nt8b(const ushort_t* __restrict__ A, const ushort_t* __restrict__ B,
               void* __restrict__ Cv, const float* __restrict__ bias,
               const float* __restrict__ resid,
               int M, int N, int K, long sAb, long sBb, long sCb)
{
  extern __shared__ char smem[];
  const ushort_t* lds = (const ushort_t*)smem;
  const int tid = threadIdx.x;
  const int l   = tid & 63;
  const int nwg = gridDim.x * gridDim.y;
  const int orig = blockIdx.y * gridDim.x + blockIdx.x;
  const int q8 = nwg >> 3, r8 = nwg & 7;
  const int xcd = orig & 7, io = orig >> 3;
  const int logical = (xcd < r8 ? xcd * (q8 + 1) : r8 * (q8 + 1) + (xcd - r8) * q8) + io;
  const int m0 = (logical / gridDim.x) * 256;
  const int n0 = (logical % gridDim.x) * 128;
  A += (long)blockIdx.z * sAb;
  B += (long)blockIdx.z * sBb;
  const long coff = (long)blockIdx.z * sCb;
  const int wid = tid >> 6;
  const int wm = (wid >> 1) * 64;
  const int wn = (wid & 1) * 64;
  int Keff = K;
  if (KLIM) Keff = min(K, m0 + 256);
  const int nt = Keff >> 5;

  const int  sg      = (((tid & 3) ^ ((tid >> 3) & 3))) * 8;
  const long rowA0   = (long)(m0 +       (tid >> 2)) * K;
  const long rowA1   = (long)(m0 + 128 + (tid >> 2)) * K;
  const long rowB0   = (long)(n0 +       (tid >> 2)) * K;
  const int  wbase16 = (tid & ~63) * 16;

#define STAGEB(TT) do {                                                       \
    const long _k  = (long)(TT) * 32;                                         \
    char* _ra = (char*)smem + ((TT) & 3) * 24576 + wbase16;                   \
    char* _rb = _ra + 16384;                                                  \
    gload_lds16(A + rowA0 + _k + sg, _ra);                                    \
    gload_lds16(A + rowA1 + _k + sg, _ra + 8192);                             \
    gload_lds16(B + rowB0 + _k + sg, _rb);                                    \
  } while (0)

  const int fr  = l & 15;
  const int fsl = (((l >> 4) ^ ((l >> 1) & 3))) * 8;

  f32x4 acc[4][4] = {};

  STAGEB(0);
  if (nt > 1) STAGEB(1);
  if (nt > 2) STAGEB(2);
  if (nt > 2)      { asm volatile("s_waitcnt vmcnt(6)" ::: "memory"); }
  else if (nt > 1) { asm volatile("s_waitcnt vmcnt(3)" ::: "memory"); }
  else             { asm volatile("s_waitcnt vmcnt(0)" ::: "memory"); }
  __builtin_amdgcn_s_barrier();
  __builtin_amdgcn_sched_barrier(0);

  for (int t = 0; t < nt; ++t) {
    const int buf = t & 3;
    const ushort_t* rA = lds + buf * 12288 +        (wm + fr) * 32 + fsl;
    const ushort_t* rB = lds + buf * 12288 + 8192 + (wn + fr) * 32 + fsl;
    bf16v8 av[4], bv[4];
#pragma unroll
    for (int mf = 0; mf < 4; mf++) av[mf] = *(const bf16v8*)(rA + mf * 512);
#pragma unroll
    for (int nf = 0; nf < 4; nf++) bv[nf] = *(const bf16v8*)(rB + nf * 512);

    if (t + 3 < nt) STAGEB(t + 3);

    __builtin_amdgcn_s_setprio(1);
#pragma unroll
    for (int mf = 0; mf < 4; mf++)
#pragma unroll
      for (int nf = 0; nf < 4; nf++)
        acc[mf][nf] = __builtin_amdgcn_mfma_f32_16x16x32_bf16(
            av[mf], bv[nf], acc[mf][nf], 0, 0, 0);
    __builtin_amdgcn_s_setprio(0);

    if (t <= nt - 4) {
      asm volatile("s_waitcnt vmcnt(6)" ::: "memory");
      __builtin_amdgcn_s_barrier();
      __builtin_amdgcn_sched_barrier(0);
    } else if (t == nt - 3) {
      asm volatile("s_waitcnt vmcnt(3)" ::: "memory");
      __builtin_amdgcn_s_barrier();
      __builtin_amdgcn_sched_barrier(0);
    } else if (t == nt - 2) {
      asm volatile("s_waitcnt vmcnt(0)" ::: "memory");
      __builtin_amdgcn_s_barrier();
      __builtin_amdgcn_sched_barrier(0);
    }
  }
#undef STAGEB

  const int lr = (l >> 4) * 4;
#pragma unroll
  for (int mf = 0; mf < 4; mf++) {
    const int row0 = m0 + wm + mf * 16 + lr;
#pragma unroll
    for (int nf = 0; nf < 4; nf++) {
      const int col = n0 + wn + nf * 16 + fr;
      const float bcol = (EPI == 4) ? bias[col] : 0.f;
#pragma unroll
      for (int r = 0; r < 4; r++) {
        float v = acc[mf][nf][r];
        const long idx = coff + (long)(row0 + r) * N + col;
        if constexpr (EPI == 0) {
          ((ushort_t*)Cv)[idx] = f2bf(v);
        } else if constexpr (EPI == 3) {
          ((float*)Cv)[idx] = v + resid[idx];
        } else {  // EPI == 4
          v += bcol;
          v = v >= 0.f ? v : SLOPE * v;
          ((float*)Cv)[idx] = v + resid[idx];
        }
      }
    }
  }
}

// ---------------------------------------------------------------------------
// m97-style 128x128 NT GEMM (4 waves, BK=32), XCD-swizzled grid.
// Fallback tiers only.
// ---------------------------------------------------------------------------
template<int EPI, bool CAUSAL, bool KLIM>
__global__ __launch_bounds__(256)
void gemm_nt(const ushort_t* __restrict__ A, const ushort_t* __restrict__ B,
             void* __restrict__ Cv, const float* __restrict__ bias,
             const float* __restrict__ resid,
             int M, int N, int K, long sAb, long sBb, long sCb)
{
  __shared__ ushort_t lA[128 * 32];
  __shared__ ushort_t lB[128 * 32];
  const int tid = threadIdx.x;
  const int w = tid >> 6;
  const int l = tid & 63;
  const int nwg = gridDim.x * gridDim.y;
  const int orig = blockIdx.y * gridDim.x + blockIdx.x;
  const int q8 = nwg >> 3, r8 = nwg & 7;
  const int xcd = orig & 7, io = orig >> 3;
  const int logical = (xcd < r8 ? xcd * (q8 + 1) : r8 * (q8 + 1) + (xcd - r8) * q8) + io;
  const int m0 = (logical / gridDim.x) * 128;
  const int n0 = (logical % gridDim.x) * 128;
  if (CAUSAL && n0 > m0 + 127) return;
  const long bz = blockIdx.z;
  A += bz * sAb;
  B += bz * sBb;
  int Keff = K;
  if (KLIM) Keff = min(K, m0 + 128);

  const ushort_t* gA = A + (long)(m0 + w * 32 + (l >> 2)) * K + (l & 3) * 8;
  const ushort_t* gB = B + (long)(n0 + w * 32 + (l >> 2)) * K + (l & 3) * 8;
  ushort_t* lAw0 = &lA[(w * 32) * 32];
  ushort_t* lAw1 = &lA[(w * 32 + 16) * 32];
  ushort_t* lBw0 = &lB[(w * 32) * 32];
  ushort_t* lBw1 = &lB[(w * 32 + 16) * 32];
  const int wm = (w >> 1) * 64, wn = (w & 1) * 64;

  f32x4 acc[4][4] = {};

  for (int k0 = 0; k0 < Keff; k0 += 32) {
    gload_lds16(gA,                 lAw0);
    gload_lds16(gA + (long)16 * K,  lAw1);
    gload_lds16(gB,                 lBw0);
    gload_lds16(gB + (long)16 * K,  lBw1);
    gA += 32; gB += 32;
    __syncthreads();

    bf16v8 af[4], bfr[4];
#pragma unroll
    for (int m = 0; m < 4; m++)
      af[m] = *(const bf16v8*)&lA[(wm + m * 16 + (l & 15)) * 32 + (l >> 4) * 8];
#pragma unroll
    for (int n = 0; n < 4; n++)
      bfr[n] = *(const bf16v8*)&lB[(wn + n * 16 + (l & 15)) * 32 + (l >> 4) * 8];
#pragma unroll
    for (int m = 0; m < 4; m++)
#pragma unroll
      for (int n = 0; n < 4; n++)
        acc[m][n] = __builtin_amdgcn_mfma_f32_16x16x32_bf16(af[m], bfr[n], acc[m][n], 0, 0, 0);
    __syncthreads();
  }

  const int lr = (l >> 4) * 4;
  const int lc = l & 15;
#pragma unroll
  for (int m = 0; m < 4; m++) {
    const int row0 = m0 + wm + m * 16 + lr;
#pragma unroll
    for (int n = 0; n < 4; n++) {
      const int col = n0 + wn + n * 16 + lc;
#pragma unroll
      for (int r = 0; r < 4; r++) {
        float v = acc[m][n][r];
        const long idx = bz * sCb + (long)(row0 + r) * N + col;
        if constexpr (EPI == 0) {
          ((ushort_t*)Cv)[idx] = f2bf(v);
        } else if constexpr (EPI == 2) {
          v += bias[col];
          v = v >= 0.f ? v : SLOPE * v;
          ((ushort_t*)Cv)[idx] = f2bf(v);
        } else if constexpr (EPI == 3) {
          ((float*)Cv)[idx] = v + resid[idx];
        } else {
          v += bias[col];
          v = v >= 0.f ? v : SLOPE * v;
          ((float*)Cv)[idx] = v + resid[idx];
        }
      }
    }
  }
}

// ---------------------------------------------------------------------------
// LayerNorm: one 256-thread block per 1024-f32 row -> bf16 out
// ---------------------------------------------------------------------------
__global__ __launch_bounds__(256)
void ln_kernel(const float* __restrict__ x, const float* __restrict__ g,
               const float* __restrict__ bta, ushort_t* __restrict__ o)
{
  const long row = blockIdx.x;
  const int tid = threadIdx.x;
  const float4 v = *((const float4*)(x + row * 1024) + tid);
  float s  = v.x + v.y + v.z + v.w;
  float ss = v.x * v.x + v.y * v.y + v.z * v.z + v.w * v.w;
  for (int o2 = 32; o2 > 0; o2 >>= 1) {
    s  += __shfl_down(s, o2);
    ss += __shfl_down(ss, o2);
  }
  __shared__ float rs[4], rss[4];
  const int w = tid >> 6, l = tid & 63;
  if (l == 0) { rs[w] = s; rss[w] = ss; }
  __syncthreads();
  if (tid == 0) {
    float a = 0, c = 0;
    for (int i = 0; i < 4; i++) { a += rs[i]; c += rss[i]; }
    rs[0] = a; rss[0] = c;
  }
  __syncthreads();
  const float mean = rs[0] * (1.f / 1024.f);
  const float var  = rss[0] * (1.f / 1024.f) - mean * mean;
  const float rstd = rsqrtf(var + 1e-5f);
  const int c0 = tid * 4;
  ushort_t* orow = o + row * 1024;
  const float* vp = (const float*)&v;
#pragma unroll
  for (int i = 0; i < 4; i++)
    orow[c0 + i] = f2bf((vp[i] - mean) * rstd * g[c0 + i] + bta[c0 + i]);
}

// ---------------------------------------------------------------------------
// Causal softmax, IN PLACE on bf16 scores (scale 1/32), zero-fill t>s.
// ---------------------------------------------------------------------------
__global__ __launch_bounds__(256)
void softmax_kernel(ushort_t* __restrict__ sc)
{
  const long row = blockIdx.x;
  const int s = (int)(row & 2047);
  const int tid = threadIdx.x;
  ushort_t* srow = sc + row * 2048;
  const int t0 = tid * 8;
  u16x8 raw = *(const u16x8*)(srow + t0);
  float v[8];
  const float rsc = 1.0f / 32.0f;
  float mx = -3e38f;
#pragma unroll
  for (int i = 0; i < 8; i++) {
    float f = bf2f(raw[i]) * rsc;
    v[i] = (t0 + i <= s) ? f : -3e38f;
    mx = fmaxf(mx, v[i]);
  }
  for (int o = 32; o > 0; o >>= 1) mx = fmaxf(mx, __shfl_down(mx, o));
  __shared__ float red[8];
  const int w = tid >> 6, l = tid & 63;
  if (l == 0) red[w] = mx;
  __syncthreads();
  if (tid == 0) {
    float m2 = red[0];
    for (int i = 1; i < 4; i++) m2 = fmaxf(m2, red[i]);
    red[0] = m2;
  }
  __syncthreads();
  const float m = red[0];
  float sum = 0.f;
#pragma unroll
  for (int i = 0; i < 8; i++) {
    float e = (t0 + i <= s) ? __expf(v[i] - m) : 0.f;
    v[i] = e; sum += e;
  }
  for (int o = 32; o > 0; o >>= 1) sum += __shfl_down(sum, o);
  if (l == 0) red[4 + w] = sum;
  __syncthreads();
  if (tid == 0) {
    float s2 = 0;
    for (int i = 0; i < 4; i++) s2 += red[4 + i];
    red[0] = 1.0f / s2;
  }
  __syncthreads();
  const float inv = red[0];
#pragma unroll
  for (int i = 0; i < 8; i++) srow[t0 + i] = f2bf(v[i] * inv);
}

// ---------------------------------------------------------------------------
// Fused cast of all three MLP weights (one launch).
// ---------------------------------------------------------------------------
__global__ __launch_bounds__(256)
void cast3_bf16(const float* __restrict__ a, const float* __restrict__ b,
                const float* __restrict__ c, ushort_t* __restrict__ oa,
                ushort_t* __restrict__ ob, ushort_t* __restrict__ oc)
{
  long i = ((long)blockIdx.x * 256 + threadIdx.x) * 4;
  const float* src; ushort_t* dst;
  if (i < 4194304L)        { src = a; dst = oa; }
  else if (i < 8388608L)   { src = b + (0 - 4194304L); dst = ob - 4194304L; }
  else                     { src = c + (0 - 8388608L); dst = oc - 8388608L; }
  float4 v = *(const float4*)(src + i);
  dst[i]     = f2bf(v.x);
  dst[i + 1] = f2bf(v.y);
  dst[i + 2] = f2bf(v.z);
  dst[i + 3] = f2bf(v.w);
}

// Transpose-cast f32[1024][1024] -> bf16[1024][1024]^T for qk (z=0), ov (z=1)
__global__ __launch_bounds__(256)
void transpose_cast2(const float* __restrict__ s0, ushort_t* __restrict__ d0,
                     const float* __restrict__ s1, ushort_t* __restrict__ d1)
{
  __shared__ ushort_t t[32][33];
  const float* in = blockIdx.z ? s1 : s0;
  ushort_t*    o  = blockIdx.z ? d1 : d0;
  const int tx = threadIdx.x & 31, ty = threadIdx.x >> 5;
  const int r0 = blockIdx.y * 32, c0 = blockIdx.x * 32;
#pragma unroll
  for (int i = 0; i < 4; i++)
    t[ty + i * 8][tx] = f2bf(in[(long)(r0 + ty + i * 8) * 1024 + c0 + tx]);
  __syncthreads();
#pragma unroll
  for (int i = 0; i < 4; i++)
    o[(long)(c0 + ty + i * 8) * 1024 + r0 + tx] = t[tx][ty + i * 8];
}

// Transpose bf16[R][C] -> bf16[C][R], batched over z (h -> hT)
__global__ __launch_bounds__(256)
void transpose_bf16(const ushort_t* __restrict__ in, ushort_t* __restrict__ o,
                    int R, int C)
{
  __shared__ ushort_t t[32][33];
  const long bz = blockIdx.z;
  in += bz * (long)R * C;
  o  += bz * (long)R * C;
  const int tx = threadIdx.x & 31, ty = threadIdx.x >> 5;
  const int r0 = blockIdx.y * 32, c0 = blockIdx.x * 32;
#pragma unroll
  for (int i = 0; i < 4; i++)
    t[ty + i * 8][tx] = in[(long)(r0 + ty + i * 8) * C + c0 + tx];
  __syncthreads();
#pragma unroll
  for (int i = 0; i < 4; i++)
    o[(long)(c0 + ty + i * 8) * R + r0 + tx] = t[tx][ty + i * 8];
}

// ---------------------------------------------------------------------------
extern "C" void kernel_launch(void* const* d_in, const int* in_sizes, int n_in,
                              void* d_out, int out_size, void* d_ws, size_t ws_size,
                              hipStream_t stream)
{
  const float* x      = (const float*)d_in[0];
  const float* qk     = (const float*)d_in[1];
  const float* ov     = (const float*)d_in[2];
  const float* ln1_g  = (const float*)d_in[3];
  const float* ln1_b  = (const float*)d_in[4];
  const float* ln2_g  = (const float*)d_in[5];
  const float* ln2_b  = (const float*)d_in[6];
  const float* W_up   = (const float*)d_in[7];
  const float* b_up   = (const float*)d_in[8];
  const float* W_h    = (const float*)d_in[9];
  const float* b_h    = (const float*)d_in[10];
  const float* W_down = (const float*)d_in[11];
  const float* b_down = (const float*)d_in[12];
  float* out = (float*)d_out;          // also holds x1 (residual stream)
  char* ws = (char*)d_ws;
  const long MB = 1024L * 1024L;

  // Arena:
  ushort_t* wqT    = (ushort_t*)(ws +   0 * MB);
  ushort_t* woT    = (ushort_t*)(ws +   2 * MB);
  ushort_t* h      = (ushort_t*)(ws +   4 * MB);
  ushort_t* hT     = (ushort_t*)(ws +  20 * MB);
  ushort_t* q      = (ushort_t*)(ws +  36 * MB);
  ushort_t* scores = (ushort_t*)(ws +  52 * MB);
  ushort_t* h2     = h;
  ushort_t* attnh  = q;
  ushort_t* wu     = hT;
  ushort_t* wd     = (ushort_t*)(ws +  28 * MB);
  ushort_t* wh     = q;
  ushort_t* a1     = (ushort_t*)(ws +  68 * MB);
  ushort_t* a2c    = (ushort_t*)(ws + 100 * MB);
  ushort_t* a2f    = (ushort_t*)(ws + 132 * MB);

  const bool ws197 = ws_size >= (size_t)(197 * MB);
  const bool ws166 = ws_size >= (size_t)(166 * MB);

  // ---- Phase A: attention ----
  transpose_cast2<<<dim3(32, 32, 2), 256, 0, stream>>>(qk, wqT, ov, woT);
  ln_kernel<<<8192, 256, 0, stream>>>(x, ln1_g, ln1_b, h);
  transpose_bf16<<<dim3(32, 64, 4), 256, 0, stream>>>(h, hT, 2048, 1024);

  // q = h @ qk   (256x128 engine, grid 256)
  gemm_nt8b<0, false><<<dim3(8, 32, 1), 512, 98304, stream>>>(
      h, wqT, q, nullptr, nullptr, 8192, 1024, 1024, 0, 0, 0);
  // scores = q @ h^T  (256x256 engine, causal skip, batched)
  gemm_nt8<0, true><<<dim3(8, 8, 4), 512, 131072, stream>>>(
      q, h, scores, nullptr, 2048, 2048, 1024,
      2048L * 1024, 2048L * 1024, 2048L * 2048);
  // probs = causal softmax(scores/32), in place
  softmax_kernel<<<8192, 256, 0, stream>>>(scores);
  // attnh = probs @ h  (256x128 engine, KLIM, batched; B = hT)
  gemm_nt8b<0, true><<<dim3(8, 8, 4), 512, 98304, stream>>>(
      scores, hT, attnh, nullptr, nullptr, 2048, 1024, 2048,
      2048L * 2048, 1024L * 2048, 2048L * 1024);
  // x1 = x + attnh @ ov  -> stored in d_out  (256x128 engine)
  gemm_nt8b<3, false><<<dim3(8, 32, 1), 512, 98304, stream>>>(
      attnh, woT, out, nullptr, x, 8192, 1024, 1024, 0, 0, 0);

  // ---- Phase B: MLP ----
  ln_kernel<<<8192, 256, 0, stream>>>(out, ln2_g, ln2_b, h2);
  cast3_bf16<<<24576, 256, 0, stream>>>(W_up, W_down, W_h, wu, wd, wh);

  if (ws197) {
    gemm_nt8<2, false><<<dim3(16, 32, 1), 512, 131072, stream>>>(
        h2, wu, a1, b_up, 8192, 4096, 1024, 0, 0, 0);
    gemm_nt8<2, false><<<dim3(16, 32, 1), 512, 131072, stream>>>(
        a1, wh, a2f, b_h, 8192, 4096, 4096, 0, 0, 0);
    gemm_nt8b<4, false><<<dim3(8, 32, 1), 512, 98304, stream>>>(
        a2f, wd, out, b_down, out, 8192, 1024, 4096, 0, 0, 0);
  } else if (ws166) {
    for (int c = 0; c < 2; c++) {
      const long r0 = (long)c * 4096;
      gemm_nt8<2, false><<<dim3(16, 16, 1), 512, 131072, stream>>>(
          h2 + r0 * 1024, wu, a1, b_up, 4096, 4096, 1024, 0, 0, 0);
      gemm_nt8<2, false><<<dim3(16, 16, 1), 512, 131072, stream>>>(
          a1, wh, a2c + r0 * 4096, b_h, 4096, 4096, 4096, 0, 0, 0);
    }
    gemm_nt<4, false, false><<<dim3(8, 64, 1), 256, 0, stream>>>(
        a2c, wd, out, b_down, out, 8192, 1024, 4096, 0, 0, 0);
  } else {
    for (int c = 0; c < 2; c++) {
      const long r0 = (long)c * 4096;
      gemm_nt8<2, false><<<dim3(16, 16, 1), 512, 131072, stream>>>(
          h2 + r0 * 1024, wu, a1, b_up, 4096, 4096, 1024, 0, 0, 0);
      gemm_nt8<2, false><<<dim3(16, 16, 1), 512, 131072, stream>>>(
          a1, wh, a2c, b_h, 4096, 4096, 4096, 0, 0, 0);
      gemm_nt<4, false, false><<<dim3(8, 32, 1), 256, 0, stream>>>(
          a2c, wd, out + r0 * 1024, b_down, out + r0 * 1024, 4096, 1024, 4096, 0, 0, 0);
    }
  }
}